// Round 1
// baseline (9016.413 us; speedup 1.0000x reference)
//
#include <hip/hip_runtime.h>
#include <hip/hip_bf16.h>
#include <math.h>

#define NEG_SLOPE 0.2f

// ---------- helpers ----------
__device__ __forceinline__ unsigned int orderKey(float f) {
    unsigned int v = __float_as_uint(f);
    return (v & 0x80000000u) ? ~v : (v | 0x80000000u);
}
__device__ __forceinline__ float decodeKey(unsigned int k) {
    return (k & 0x80000000u) ? __uint_as_float(k & 0x7FFFFFFFu)
                             : __uint_as_float(~k);
}
__device__ __forceinline__ void atomicMaxFloatKey(unsigned int* addr, float v) {
    atomicMax(addr, orderKey(v));
}

// ---------- init ----------
__global__ void k_fill_u32(unsigned int* __restrict__ p, int n, unsigned int v) {
    int i = blockIdx.x * blockDim.x + threadIdx.x;
    if (i < n) p[i] = v;
}
__global__ void k_decode_max(unsigned int* __restrict__ p, int n) {
    int i = blockIdx.x * blockDim.x + threadIdx.x;
    if (i < n) p[i] = __float_as_uint(decodeKey(p[i]));
}

// ---------- GEMM: C[n,j] = sum_k X[n,k] * W[k,j]; block = M threads, one row per block ----------
__global__ void k_gemm(const float* __restrict__ X, const float* __restrict__ W,
                       float* __restrict__ C, int K, int M) {
    extern __shared__ float xs[];
    int n = blockIdx.x;
    for (int k = threadIdx.x; k < K; k += blockDim.x) xs[k] = X[(size_t)n * K + k];
    __syncthreads();
    int j = threadIdx.x;
    float acc = 0.f;
    for (int k = 0; k < K; ++k) acc = fmaf(xs[k], W[(size_t)k * M + j], acc);
    C[(size_t)n * M + j] = acc;
}

// ---------- attention logits: al_s[n,h] = <H[n,h,:], a_src[h,:]>, same for dst ----------
__global__ void k_attn_logits(const float* __restrict__ H, const float* __restrict__ a_src,
                              const float* __restrict__ a_dst, float* __restrict__ al_s,
                              float* __restrict__ al_d, int N, int heads, int ch) {
    int i = blockIdx.x * blockDim.x + threadIdx.x;
    if (i >= N * heads) return;
    int n = i / heads, h = i % heads;
    const float* hp = H + (size_t)n * heads * ch + (size_t)h * ch;
    const float* as = a_src + (size_t)h * ch;
    const float* ad = a_dst + (size_t)h * ch;
    float s = 0.f, d = 0.f;
    for (int c = 0; c < ch; ++c) {
        float v = hp[c];
        s = fmaf(v, as[c], s);
        d = fmaf(v, ad[c], d);
    }
    al_s[i] = s;
    al_d[i] = d;
}

// ---------- edge pass 1: segment max over dst (atomic ordered-uint max) ----------
__global__ void k_edge_max(const int* __restrict__ ei, int E, int Etot, int heads,
                           const float* __restrict__ als, const float* __restrict__ ald,
                           unsigned int* __restrict__ mkey) {
    int t = blockIdx.x * blockDim.x + threadIdx.x;
    if (t >= Etot * heads) return;
    int e = t / heads, h = t - (t / heads) * heads;
    int s, d;
    if (e < E) { s = ei[e]; d = ei[E + e]; } else { s = d = e - E; }
    float v = als[s * heads + h] + ald[d * heads + h];
    v = v >= 0.f ? v : NEG_SLOPE * v;
    atomicMaxFloatKey(&mkey[d * heads + h], v);
}

// ---------- edge pass 2: segment sum of exp(e - m[dst]) ----------
__global__ void k_edge_sumexp(const int* __restrict__ ei, int E, int Etot, int heads,
                              const float* __restrict__ als, const float* __restrict__ ald,
                              const float* __restrict__ m, float* __restrict__ ssum) {
    int t = blockIdx.x * blockDim.x + threadIdx.x;
    if (t >= Etot * heads) return;
    int e = t / heads, h = t - (t / heads) * heads;
    int s, d;
    if (e < E) { s = ei[e]; d = ei[E + e]; } else { s = d = e - E; }
    float v = als[s * heads + h] + ald[d * heads + h];
    v = v >= 0.f ? v : NEG_SLOPE * v;
    float ex = expf(v - m[d * heads + h]);
    atomicAdd(&ssum[d * heads + h], ex);
}

// ---------- edge pass 3: out[dst,h,:] += alpha * H[src,h,:]  (cpt channels per thread) ----------
__global__ void k_edge_scatter(const int* __restrict__ ei, int E, int Etot, int heads,
                               int ch, int cpt,
                               const float* __restrict__ als, const float* __restrict__ ald,
                               const float* __restrict__ m, const float* __restrict__ ssum,
                               const float* __restrict__ H, float* __restrict__ out) {
    int nchunk = ch / cpt;
    int t = blockIdx.x * blockDim.x + threadIdx.x;
    if (t >= Etot * heads * nchunk) return;
    int chunk = t % nchunk;
    t /= nchunk;
    int h = t % heads;
    int e = t / heads;
    int s, d;
    if (e < E) { s = ei[e]; d = ei[E + e]; } else { s = d = e - E; }
    float v = als[s * heads + h] + ald[d * heads + h];
    v = v >= 0.f ? v : NEG_SLOPE * v;
    float alpha = expf(v - m[d * heads + h]) / ssum[d * heads + h];
    const float* hp = H + (size_t)s * heads * ch + (size_t)h * ch + chunk * cpt;
    float* op = out + (size_t)d * heads * ch + (size_t)h * ch + chunk * cpt;
    for (int c = 0; c < cpt; ++c) atomicAdd(&op[c], alpha * hp[c]);
}

// ---------- bias + relu in place (M = 256) ----------
__global__ void k_bias_relu(float* __restrict__ B, const float* __restrict__ bias, int total) {
    int i = blockIdx.x * blockDim.x + threadIdx.x;
    if (i >= total) return;
    B[i] = fmaxf(B[i] + bias[i & 255], 0.f);
}

// ---------- pooling: pooled[batch[n], d] += out2[n,d] + b2[d] ----------
__global__ void k_pool(const float* __restrict__ B, const float* __restrict__ bias,
                       const int* __restrict__ batch, float* __restrict__ pooled, int N) {
    int i = blockIdx.x * blockDim.x + threadIdx.x;
    if (i >= N * 256) return;
    int n = i >> 8, d = i & 255;
    atomicAdd(&pooled[batch[n] * 256 + d], B[i] + bias[d]);
}
__global__ void k_cnt(const int* __restrict__ batch, float* __restrict__ cnt, int N) {
    int i = blockIdx.x * blockDim.x + threadIdx.x;
    if (i < N) atomicAdd(&cnt[batch[i]], 1.0f);
}

// ---------- final: out[g,l] = (1/cnt[g]) * <pooled[g,:], lin_w[:,l]> + lin_b[l] ----------
__global__ void k_final(const float* __restrict__ pooled, const float* __restrict__ cnt,
                        const float* __restrict__ lw, const float* __restrict__ lb,
                        float* __restrict__ out, int G, int L, int D) {
    int i = blockIdx.x * blockDim.x + threadIdx.x;
    if (i >= G * L) return;
    int g = i / L, l = i % L;
    float acc = 0.f;
    for (int d = 0; d < D; ++d) acc = fmaf(pooled[g * D + d], lw[d * L + l], acc);
    float inv = 1.0f / fmaxf(cnt[g], 1.0f);
    out[i] = acc * inv + lb[l];
}

extern "C" void kernel_launch(void* const* d_in, const int* in_sizes, int n_in,
                              void* d_out, int out_size, void* d_ws, size_t ws_size,
                              hipStream_t stream) {
    const float* x   = (const float*)d_in[0];
    const int*   ei  = (const int*)d_in[1];
    const int*   bat = (const int*)d_in[2];
    const float* W1  = (const float*)d_in[3];
    const float* as1 = (const float*)d_in[4];
    const float* ad1 = (const float*)d_in[5];
    const float* b1  = (const float*)d_in[6];
    const float* W2  = (const float*)d_in[7];
    const float* as2 = (const float*)d_in[8];
    const float* ad2 = (const float*)d_in[9];
    const float* b2  = (const float*)d_in[10];
    const float* lw  = (const float*)d_in[11];
    const float* lb  = (const float*)d_in[12];
    float* out = (float*)d_out;

    const int N = in_sizes[2];        // 10000
    const int E = in_sizes[1] / 2;    // 320000
    const int FIN = 128, H1 = 16, HC = 256, D = 256, G = 64, L = 10;
    const int Etot = E + N;

    // workspace layout (floats)
    float* A    = (float*)d_ws;              // [N,256] h1 then h2
    float* B    = A + (size_t)N * 256;       // [N,256] out1 then out2
    float* als1 = B + (size_t)N * 256;       // [N,16]
    float* ald1 = als1 + (size_t)N * H1;
    float* m1   = ald1 + (size_t)N * H1;     // keys then floats
    float* s1   = m1 + (size_t)N * H1;
    float* als2 = s1 + (size_t)N * H1;       // [N]
    float* ald2 = als2 + N;
    float* m2   = ald2 + N;
    float* s2   = m2 + N;
    float* pooled = s2 + N;                  // [G,256]
    float* cnt  = pooled + (size_t)G * D;    // [G]

    const unsigned int NEG_INF_KEY = 0x007FFFFFu;  // orderKey(-inf)
    const int BS = 256;
    auto nb = [](int n, int b) { return (n + b - 1) / b; };

    // ---- init accumulators ----
    hipMemsetAsync(s1, 0, (size_t)N * H1 * 4, stream);
    hipMemsetAsync(B, 0, (size_t)N * 256 * 4, stream);
    hipMemsetAsync(s2, 0, (size_t)N * 4, stream);
    hipMemsetAsync(pooled, 0, ((size_t)G * D + G) * 4, stream);
    k_fill_u32<<<nb(N * H1, BS), BS, 0, stream>>>((unsigned int*)m1, N * H1, NEG_INF_KEY);
    k_fill_u32<<<nb(N, BS), BS, 0, stream>>>((unsigned int*)m2, N, NEG_INF_KEY);

    // ---- layer 1 ----
    k_gemm<<<N, 256, FIN * 4, stream>>>(x, W1, A, FIN, 256);
    k_attn_logits<<<nb(N * H1, BS), BS, 0, stream>>>(A, as1, ad1, als1, ald1, N, H1, 16);
    k_edge_max<<<nb(Etot * H1, BS), BS, 0, stream>>>(ei, E, Etot, H1, als1, ald1, (unsigned int*)m1);
    k_decode_max<<<nb(N * H1, BS), BS, 0, stream>>>((unsigned int*)m1, N * H1);
    k_edge_sumexp<<<nb(Etot * H1, BS), BS, 0, stream>>>(ei, E, Etot, H1, als1, ald1, m1, s1);
    k_edge_scatter<<<nb(Etot * H1, BS), BS, 0, stream>>>(ei, E, Etot, H1, 16, 16,
                                                         als1, ald1, m1, s1, A, B);
    k_bias_relu<<<nb(N * 256, BS), BS, 0, stream>>>(B, b1, N * 256);

    // ---- layer 2 ----
    k_gemm<<<N, 256, 256 * 4, stream>>>(B, W2, A, HC, 256);
    hipMemsetAsync(B, 0, (size_t)N * 256 * 4, stream);  // re-zero for out2
    k_attn_logits<<<nb(N, BS), BS, 0, stream>>>(A, as2, ad2, als2, ald2, N, 1, D);
    k_edge_max<<<nb(Etot, BS), BS, 0, stream>>>(ei, E, Etot, 1, als2, ald2, (unsigned int*)m2);
    k_decode_max<<<nb(N, BS), BS, 0, stream>>>((unsigned int*)m2, N);
    k_edge_sumexp<<<nb(Etot, BS), BS, 0, stream>>>(ei, E, Etot, 1, als2, ald2, m2, s2);
    k_edge_scatter<<<nb(Etot * 16, BS), BS, 0, stream>>>(ei, E, Etot, 1, D, 16,
                                                         als2, ald2, m2, s2, A, B);

    // ---- pool + final linear ----
    k_cnt<<<nb(N, BS), BS, 0, stream>>>(bat, cnt, N);
    k_pool<<<nb(N * 256, BS), BS, 0, stream>>>(B, b2, bat, pooled, N);
    k_final<<<nb(G * L, 64), 64, 0, stream>>>(pooled, cnt, lw, lb, out, G, L, D);
}

// Round 2
// 675.100 us; speedup vs baseline: 13.3557x; 13.3557x over previous
//
#include <hip/hip_runtime.h>
#include <hip/hip_bf16.h>
#include <math.h>

#define NEG_SLOPE 0.2f

// ---------- small utils ----------
__global__ void k_zero_i32(int* __restrict__ p, int n) {
    int i = blockIdx.x * blockDim.x + threadIdx.x;
    if (i < n) p[i] = 0;
}

// ---------- CSR build over dst ----------
__global__ void k_count(const int* __restrict__ ei, int E, int N, int* __restrict__ counts) {
    int e = blockIdx.x * blockDim.x + threadIdx.x;
    int Etot = E + N;
    if (e >= Etot) return;
    int d = (e < E) ? ei[E + e] : (e - E);
    atomicAdd(&counts[d], 1);
}

// exclusive scan of counts[N] -> rowptr[N+1]; single block of 256, chunked
__global__ void k_scan(const int* __restrict__ counts, int* __restrict__ rowptr, int N) {
    __shared__ int buf[256];
    __shared__ int carry;
    if (threadIdx.x == 0) carry = 0;
    __syncthreads();
    for (int base = 0; base < N; base += 256) {
        int i = base + threadIdx.x;
        int v = (i < N) ? counts[i] : 0;
        buf[threadIdx.x] = v;
        __syncthreads();
        for (int off = 1; off < 256; off <<= 1) {
            int t = (threadIdx.x >= off) ? buf[threadIdx.x - off] : 0;
            __syncthreads();
            buf[threadIdx.x] += t;
            __syncthreads();
        }
        if (i < N) rowptr[i] = carry + buf[threadIdx.x] - v;
        int total = buf[255];
        __syncthreads();
        if (threadIdx.x == 0) carry += total;
        __syncthreads();
    }
    if (threadIdx.x == 0) rowptr[N] = carry;
}

__global__ void k_copy_i32(const int* __restrict__ src, int* __restrict__ dst, int n) {
    int i = blockIdx.x * blockDim.x + threadIdx.x;
    if (i < n) dst[i] = src[i];
}

__global__ void k_fill_csr(const int* __restrict__ ei, int E, int N,
                           int* __restrict__ cursor, int* __restrict__ col) {
    int e = blockIdx.x * blockDim.x + threadIdx.x;
    int Etot = E + N;
    if (e >= Etot) return;
    int s, d;
    if (e < E) { s = ei[e]; d = ei[E + e]; } else { s = d = e - E; }
    int pos = atomicAdd(&cursor[d], 1);
    col[pos] = s;
}

// ---------- GEMM: C[n,j] = sum_k X[n,k] * W[k,j]; one row per block of 256 ----------
__global__ void k_gemm(const float* __restrict__ X, const float* __restrict__ W,
                       float* __restrict__ C, int K, int M) {
    extern __shared__ float xs[];
    int n = blockIdx.x;
    for (int k = threadIdx.x; k < K; k += blockDim.x) xs[k] = X[(size_t)n * K + k];
    __syncthreads();
    int j = threadIdx.x;
    float acc = 0.f;
    for (int k = 0; k < K; ++k) acc = fmaf(xs[k], W[(size_t)k * M + j], acc);
    C[(size_t)n * M + j] = acc;
}

// ---------- attention logits ----------
__global__ void k_attn_logits(const float* __restrict__ H, const float* __restrict__ a_src,
                              const float* __restrict__ a_dst, float* __restrict__ al_s,
                              float* __restrict__ al_d, int N, int heads, int ch) {
    int i = blockIdx.x * blockDim.x + threadIdx.x;
    if (i >= N * heads) return;
    int n = i / heads, h = i % heads;
    const float* hp = H + (size_t)n * heads * ch + (size_t)h * ch;
    const float* as = a_src + (size_t)h * ch;
    const float* ad = a_dst + (size_t)h * ch;
    float s = 0.f, d = 0.f;
    for (int c = 0; c < ch; ++c) {
        float v = hp[c];
        s = fmaf(v, as[c], s);
        d = fmaf(v, ad[c], d);
    }
    al_s[i] = s;
    al_d[i] = d;
}

// ---------- fused GAT gather: one block (256 thr) per dst node ----------
// thread t owns output element t; h = t / CH.  Two edge passes:
//   pass 1: m = max leaky(als[src,h] + ald[dst,h])
//   pass 2: ssum += exp(e-m); acc += exp(e-m) * H[src*256 + t]
// out[n,t] = acc/ssum + bias[t]  (optional relu)
template <int HEADS, int CH, bool RELU>
__global__ void k_gat_gather(const int* __restrict__ rowptr, const int* __restrict__ col,
                             const float* __restrict__ H, const float* __restrict__ als,
                             const float* __restrict__ ald, const float* __restrict__ bias,
                             float* __restrict__ out) {
    int n = blockIdx.x;
    int t = threadIdx.x;
    int h = t / CH;
    int start = rowptr[n], end = rowptr[n + 1];
    float aldv = ald[n * HEADS + h];

    float m = -INFINITY;
    for (int i = start; i < end; ++i) {
        int s = col[i];
        float v = als[s * HEADS + h] + aldv;
        v = v >= 0.f ? v : NEG_SLOPE * v;
        m = fmaxf(m, v);
    }
    float ssum = 0.f, acc = 0.f;
    for (int i = start; i < end; ++i) {
        int s = col[i];
        float v = als[s * HEADS + h] + aldv;
        v = v >= 0.f ? v : NEG_SLOPE * v;
        float ex = expf(v - m);
        ssum += ex;
        acc = fmaf(ex, H[(size_t)s * 256 + t], acc);
    }
    float r = acc / ssum + bias[t];
    if (RELU) r = fmaxf(r, 0.f);
    out[(size_t)n * 256 + t] = r;
}

// ---------- pooling ----------
__global__ void k_pool(const float* __restrict__ B, const int* __restrict__ batch,
                       float* __restrict__ pooled, int N) {
    int i = blockIdx.x * blockDim.x + threadIdx.x;
    if (i >= N * 256) return;
    int n = i >> 8, d = i & 255;
    atomicAdd(&pooled[batch[n] * 256 + d], B[i]);
}
__global__ void k_cnt(const int* __restrict__ batch, float* __restrict__ cnt, int N) {
    int i = blockIdx.x * blockDim.x + threadIdx.x;
    if (i < N) atomicAdd(&cnt[batch[i]], 1.0f);
}

// ---------- final linear ----------
__global__ void k_final(const float* __restrict__ pooled, const float* __restrict__ cnt,
                        const float* __restrict__ lw, const float* __restrict__ lb,
                        float* __restrict__ out, int G, int L, int D) {
    int i = blockIdx.x * blockDim.x + threadIdx.x;
    if (i >= G * L) return;
    int g = i / L, l = i % L;
    float acc = 0.f;
    for (int d = 0; d < D; ++d) acc = fmaf(pooled[g * D + d], lw[d * L + l], acc);
    float inv = 1.0f / fmaxf(cnt[g], 1.0f);
    out[i] = acc * inv + lb[l];
}

extern "C" void kernel_launch(void* const* d_in, const int* in_sizes, int n_in,
                              void* d_out, int out_size, void* d_ws, size_t ws_size,
                              hipStream_t stream) {
    const float* x   = (const float*)d_in[0];
    const int*   ei  = (const int*)d_in[1];
    const int*   bat = (const int*)d_in[2];
    const float* W1  = (const float*)d_in[3];
    const float* as1 = (const float*)d_in[4];
    const float* ad1 = (const float*)d_in[5];
    const float* b1  = (const float*)d_in[6];
    const float* W2  = (const float*)d_in[7];
    const float* as2 = (const float*)d_in[8];
    const float* ad2 = (const float*)d_in[9];
    const float* b2  = (const float*)d_in[10];
    const float* lw  = (const float*)d_in[11];
    const float* lb  = (const float*)d_in[12];
    float* out = (float*)d_out;

    const int N = in_sizes[2];        // 10000
    const int E = in_sizes[1] / 2;    // 320000
    const int FIN = 128, H1 = 16, HC = 256, D = 256, G = 64, L = 10;
    const int Etot = E + N;

    // workspace layout (floats)
    float* A    = (float*)d_ws;              // [N,256] h1 then h2
    float* B    = A + (size_t)N * 256;       // [N,256] out1 then out2
    float* als1 = B + (size_t)N * 256;       // [N,16]
    float* ald1 = als1 + (size_t)N * H1;
    float* als2 = ald1 + (size_t)N * H1;     // [N]
    float* ald2 = als2 + N;
    float* pooled = ald2 + N;                // [G,256]
    float* cnt  = pooled + (size_t)G * D;    // [G]
    int* counts = (int*)(cnt + G);           // [N]
    int* rowptr = counts + N;                // [N+1]
    int* cursor = rowptr + N + 1;            // [N]
    int* col    = cursor + N;                // [Etot]

    const int BS = 256;
    auto nb = [](int n, int b) { return (n + b - 1) / b; };

    // ---- CSR build (dst-indexed) ----
    k_zero_i32<<<nb(N, BS), BS, 0, stream>>>(counts, N);
    k_count<<<nb(Etot, BS), BS, 0, stream>>>(ei, E, N, counts);
    k_scan<<<1, 256, 0, stream>>>(counts, rowptr, N);
    k_copy_i32<<<nb(N, BS), BS, 0, stream>>>(rowptr, cursor, N);
    k_fill_csr<<<nb(Etot, BS), BS, 0, stream>>>(ei, E, N, cursor, col);

    // ---- zero pooled/cnt ----
    hipMemsetAsync(pooled, 0, ((size_t)G * D + G) * 4, stream);

    // ---- layer 1 ----
    k_gemm<<<N, 256, FIN * 4, stream>>>(x, W1, A, FIN, 256);
    k_attn_logits<<<nb(N * H1, BS), BS, 0, stream>>>(A, as1, ad1, als1, ald1, N, H1, 16);
    k_gat_gather<16, 16, true><<<N, 256, 0, stream>>>(rowptr, col, A, als1, ald1, b1, B);

    // ---- layer 2 ----
    k_gemm<<<N, 256, 256 * 4, stream>>>(B, W2, A, HC, 256);
    k_attn_logits<<<nb(N, BS), BS, 0, stream>>>(A, as2, ad2, als2, ald2, N, 1, D);
    k_gat_gather<1, 256, false><<<N, 256, 0, stream>>>(rowptr, col, A, als2, ald2, b2, B);

    // ---- pool + final linear ----
    k_cnt<<<nb(N, BS), BS, 0, stream>>>(bat, cnt, N);
    k_pool<<<nb(N * 256, BS), BS, 0, stream>>>(B, bat, pooled, N);
    k_final<<<nb(G * L, 64), 64, 0, stream>>>(pooled, cnt, lw, lb, out, G, L, D);
}

// Round 3
// 297.799 us; speedup vs baseline: 30.2769x; 2.2670x over previous
//
#include <hip/hip_runtime.h>
#include <hip/hip_bf16.h>
#include <math.h>

#define NEG_SLOPE 0.2f
// wave-internal LDS ordering: ds ops from one wave complete in order once
// lgkmcnt drains; "memory" stops compiler reordering. No __syncthreads needed
// (each wave owns a private LDS slice; degrees differ per wave -> barriers UB).
#define LDS_FENCE() asm volatile("s_waitcnt lgkmcnt(0)" ::: "memory")

// ---------- small utils ----------
__global__ void k_zero_i32(int* __restrict__ p, int n) {
    int i = blockIdx.x * blockDim.x + threadIdx.x;
    if (i < n) p[i] = 0;
}

// ---------- CSR build over dst ----------
__global__ void k_count(const int* __restrict__ ei, int E, int N, int* __restrict__ counts) {
    int e = blockIdx.x * blockDim.x + threadIdx.x;
    int Etot = E + N;
    if (e >= Etot) return;
    int d = (e < E) ? ei[E + e] : (e - E);
    atomicAdd(&counts[d], 1);
}

__global__ void k_scan(const int* __restrict__ counts, int* __restrict__ rowptr, int N) {
    __shared__ int buf[1024];
    __shared__ int carry;
    if (threadIdx.x == 0) carry = 0;
    __syncthreads();
    for (int base = 0; base < N; base += 1024) {
        int i = base + threadIdx.x;
        int v = (i < N) ? counts[i] : 0;
        buf[threadIdx.x] = v;
        __syncthreads();
        for (int off = 1; off < 1024; off <<= 1) {
            int t = (threadIdx.x >= off) ? buf[threadIdx.x - off] : 0;
            __syncthreads();
            buf[threadIdx.x] += t;
            __syncthreads();
        }
        if (i < N) rowptr[i] = carry + buf[threadIdx.x] - v;
        int total = buf[1023];
        __syncthreads();
        if (threadIdx.x == 0) carry += total;
        __syncthreads();
    }
    if (threadIdx.x == 0) rowptr[N] = carry;
}

__global__ void k_copy_i32(const int* __restrict__ src, int* __restrict__ dst, int n) {
    int i = blockIdx.x * blockDim.x + threadIdx.x;
    if (i < n) dst[i] = src[i];
}

__global__ void k_fill_csr(const int* __restrict__ ei, int E, int N,
                           int* __restrict__ cursor, int* __restrict__ col) {
    int e = blockIdx.x * blockDim.x + threadIdx.x;
    int Etot = E + N;
    if (e >= Etot) return;
    int s, d;
    if (e < E) { s = ei[e]; d = ei[E + e]; } else { s = d = e - E; }
    int pos = atomicAdd(&cursor[d], 1);
    col[pos] = s;
}

// ---------- tiled GEMM: C[n,j] = sum_k X[n,k]*W[k,j], M=256 cols ----------
// block: 16 rows x 256 cols; threads (64,4): cx = cols 4cx..4cx+3, ry = rows ry*4..+3
template <int K>
__global__ __launch_bounds__(256) void k_gemm_t(const float* __restrict__ X,
                                                const float* __restrict__ W,
                                                float* __restrict__ C, int N) {
    __shared__ float xs[16][K];
    int t = threadIdx.x;
    int n0 = blockIdx.x * 16;
    for (int idx = t; idx < 16 * K; idx += 256) {
        int r = idx / K, k = idx % K;
        int n = n0 + r;
        xs[r][k] = (n < N) ? X[(size_t)n * K + k] : 0.f;
    }
    __syncthreads();
    int cx = t & 63, ry = t >> 6;
    float4 acc[4] = {};
#pragma unroll 4
    for (int k = 0; k < K; ++k) {
        float4 w4 = *(const float4*)(W + (size_t)k * 256 + cx * 4);
#pragma unroll
        for (int rr = 0; rr < 4; ++rr) {
            float xv = xs[ry * 4 + rr][k];
            acc[rr].x = fmaf(xv, w4.x, acc[rr].x);
            acc[rr].y = fmaf(xv, w4.y, acc[rr].y);
            acc[rr].z = fmaf(xv, w4.z, acc[rr].z);
            acc[rr].w = fmaf(xv, w4.w, acc[rr].w);
        }
    }
#pragma unroll
    for (int rr = 0; rr < 4; ++rr) {
        int n = n0 + ry * 4 + rr;
        if (n < N) *(float4*)(C + (size_t)n * 256 + cx * 4) = acc[rr];
    }
}

// ---------- layer-1 attention logits: thread per (n,h), ch=16 ----------
__global__ void k_logits1(const float* __restrict__ H, const float* __restrict__ a_src,
                          const float* __restrict__ a_dst, float* __restrict__ als,
                          float* __restrict__ ald, int NH) {
    int i = blockIdx.x * blockDim.x + threadIdx.x;
    if (i >= NH) return;
    int h = i & 15;
    const float4* hp = (const float4*)(H + (size_t)i * 16);  // i*16 == n*256 + h*16
    const float4* as = (const float4*)(a_src + h * 16);
    const float4* ad = (const float4*)(a_dst + h * 16);
    float s = 0.f, d = 0.f;
#pragma unroll
    for (int q = 0; q < 4; ++q) {
        float4 hv = hp[q], sv = as[q], dv = ad[q];
        s += hv.x * sv.x + hv.y * sv.y + hv.z * sv.z + hv.w * sv.w;
        d += hv.x * dv.x + hv.y * dv.y + hv.z * dv.z + hv.w * dv.w;
    }
    als[i] = s;
    ald[i] = d;
}

// ---------- layer-2 attention logits: wave per node, D=256 ----------
__global__ __launch_bounds__(256) void k_logits2(const float* __restrict__ H,
                                                 const float* __restrict__ a_src,
                                                 const float* __restrict__ a_dst,
                                                 float* __restrict__ als,
                                                 float* __restrict__ ald, int N) {
    int wave = threadIdx.x >> 6, lane = threadIdx.x & 63;
    int n = blockIdx.x * 4 + wave;
    if (n >= N) return;
    float4 hv = *(const float4*)(H + (size_t)n * 256 + lane * 4);
    float4 sv = *(const float4*)(a_src + lane * 4);
    float4 dv = *(const float4*)(a_dst + lane * 4);
    float s = hv.x * sv.x + hv.y * sv.y + hv.z * sv.z + hv.w * sv.w;
    float d = hv.x * dv.x + hv.y * dv.y + hv.z * dv.z + hv.w * dv.w;
#pragma unroll
    for (int off = 32; off >= 1; off >>= 1) {
        s += __shfl_xor(s, off);
        d += __shfl_xor(d, off);
    }
    if (lane == 0) { als[n] = s; ald[n] = d; }
}

// ---------- fused GAT gather, 1 head (D=256): one wave per dst node ----------
// no max-subtraction: logits are O(+-9), exp() safe in fp32; alpha = w/sum(w).
__global__ __launch_bounds__(256) void k_gather_h1(
    const int* __restrict__ rowptr, const int* __restrict__ col,
    const float* __restrict__ H, const float* __restrict__ als,
    const float* __restrict__ ald, const float* __restrict__ bias,
    float* __restrict__ out, int N) {
    __shared__ float2 sw[4][64];
    int wave = threadIdx.x >> 6, lane = threadIdx.x & 63;
    int n = blockIdx.x * 4 + wave;
    if (n >= N) return;
    int start = rowptr[n], end = rowptr[n + 1];
    float aldv = ald[n];
    float4 acc = {0.f, 0.f, 0.f, 0.f};
    float swsum = 0.f;
    for (int base = start; base < end; base += 64) {
        int len = min(64, end - base);
        int s = 0;
        float w = 0.f;
        if (lane < len) {
            s = col[base + lane];
            float v = als[s] + aldv;
            v = v >= 0.f ? v : NEG_SLOPE * v;
            w = __expf(v);
        }
        swsum += w;
        sw[wave][lane] = make_float2(__int_as_float(s), w);
        LDS_FENCE();
#pragma unroll 4
        for (int e = 0; e < len; ++e) {
            float2 p = sw[wave][e];
            int se = __float_as_int(p.x);
            float we = p.y;
            float4 hv = *(const float4*)(H + (size_t)se * 256 + lane * 4);
            acc.x = fmaf(we, hv.x, acc.x);
            acc.y = fmaf(we, hv.y, acc.y);
            acc.z = fmaf(we, hv.z, acc.z);
            acc.w = fmaf(we, hv.w, acc.w);
        }
        LDS_FENCE();
    }
#pragma unroll
    for (int off = 32; off >= 1; off >>= 1) swsum += __shfl_xor(swsum, off);
    float inv = 1.0f / swsum;
    float4 b4 = *(const float4*)(bias + lane * 4);
    float4 r;
    r.x = fmaf(acc.x, inv, b4.x);
    r.y = fmaf(acc.y, inv, b4.y);
    r.z = fmaf(acc.z, inv, b4.z);
    r.w = fmaf(acc.w, inv, b4.w);
    *(float4*)(out + (size_t)n * 256 + lane * 4) = r;
}

// ---------- fused GAT gather, 16 heads x 16 ch: one wave per dst node ----------
// lane owns channels 4*lane..4*lane+3 (head = lane>>2). Chunks of 32 edges:
// staging: 8 steps, lane j computes w for (edge = k*4 + j/16, head = j&15).
__global__ __launch_bounds__(256) void k_gather_h16(
    const int* __restrict__ rowptr, const int* __restrict__ col,
    const float* __restrict__ H, const float* __restrict__ als,
    const float* __restrict__ ald, const float* __restrict__ bias,
    float* __restrict__ out, int N) {
    __shared__ int s_lds[4][32];
    __shared__ float w_lds[4][32 * 16];
    int wave = threadIdx.x >> 6, lane = threadIdx.x & 63;
    int n = blockIdx.x * 4 + wave;
    if (n >= N) return;
    int start = rowptr[n], end = rowptr[n + 1];
    int hW = lane & 15;          // head this lane computes logits for
    int eW = lane >> 4;          // edge sub-slot (0..3)
    int hA = lane >> 2;          // head this lane accumulates for
    float aldW = ald[n * 16 + hW];
    float4 acc = {0.f, 0.f, 0.f, 0.f};
    float swp = 0.f;             // partial sum of w for head hW
    for (int base = start; base < end; base += 32) {
        int len = min(32, end - base);
        if (lane < 32) s_lds[wave][lane] = (lane < len) ? col[base + lane] : 0;
        LDS_FENCE();
#pragma unroll
        for (int k = 0; k < 8; ++k) {
            int esub = k * 4 + eW;
            float w = 0.f;
            if (esub < len) {
                int s = s_lds[wave][esub];
                float v = als[s * 16 + hW] + aldW;
                v = v >= 0.f ? v : NEG_SLOPE * v;
                w = __expf(v);
            }
            w_lds[wave][esub * 16 + hW] = w;   // linear in lane: conflict-free
            swp += w;
        }
        LDS_FENCE();
#pragma unroll 4
        for (int e = 0; e < len; ++e) {
            int se = s_lds[wave][e];
            float we = w_lds[wave][e * 16 + hA];
            float4 hv = *(const float4*)(H + (size_t)se * 256 + lane * 4);
            acc.x = fmaf(we, hv.x, acc.x);
            acc.y = fmaf(we, hv.y, acc.y);
            acc.z = fmaf(we, hv.z, acc.z);
            acc.w = fmaf(we, hv.w, acc.w);
        }
        LDS_FENCE();
    }
    // per-head sums: lanes with equal (lane&15) hold partials
    swp += __shfl_xor(swp, 32);
    swp += __shfl_xor(swp, 16);
    float inv = 1.0f / __shfl(swp, hA);   // any lane with (lane&15)==hA, lane hA works
    float4 b4 = *(const float4*)(bias + lane * 4);
    float4 r;
    r.x = fmaxf(fmaf(acc.x, inv, b4.x), 0.f);
    r.y = fmaxf(fmaf(acc.y, inv, b4.y), 0.f);
    r.z = fmaxf(fmaf(acc.z, inv, b4.z), 0.f);
    r.w = fmaxf(fmaf(acc.w, inv, b4.w), 0.f);
    *(float4*)(out + (size_t)n * 256 + lane * 4) = r;
}

// ---------- segmented mean-pool (batch is sorted): block per (graph, quarter) ----------
__device__ __forceinline__ int lower_bound_i(const int* __restrict__ a, int n, int v) {
    int lo = 0, hi = n;
    while (lo < hi) {
        int mid = (lo + hi) >> 1;
        if (a[mid] < v) lo = mid + 1; else hi = mid;
    }
    return lo;
}

__global__ __launch_bounds__(256) void k_pool_seg(const float* __restrict__ B,
                                                  const int* __restrict__ batch,
                                                  float* __restrict__ pooled4,
                                                  float* __restrict__ cnt, int N, int G) {
    int g = blockIdx.x >> 2, seg = blockIdx.x & 3;
    int lo = lower_bound_i(batch, N, g);
    int hi = lower_bound_i(batch, N, g + 1);
    int len = hi - lo;
    int per = (len + 3) >> 2;
    int s0 = lo + seg * per;
    int s1 = min(hi, s0 + per);
    float acc = 0.f;
#pragma unroll 4
    for (int r = s0; r < s1; ++r) acc += B[(size_t)r * 256 + threadIdx.x];
    pooled4[((size_t)(seg * G + g)) * 256 + threadIdx.x] = acc;
    if (seg == 0 && threadIdx.x == 0) cnt[g] = (float)len;
}

// ---------- final linear: wave per (g,l) ----------
__global__ __launch_bounds__(256) void k_final(const float* __restrict__ pooled4,
                                               const float* __restrict__ cnt,
                                               const float* __restrict__ lw,
                                               const float* __restrict__ lb,
                                               float* __restrict__ out, int G, int L) {
    int wave = threadIdx.x >> 6, lane = threadIdx.x & 63;
    int i = blockIdx.x * 4 + wave;
    if (i >= G * L) return;
    int g = i / L, l = i - g * L;
    float4 p = {0.f, 0.f, 0.f, 0.f};
#pragma unroll
    for (int seg = 0; seg < 4; ++seg) {
        float4 q = *(const float4*)(pooled4 + ((size_t)(seg * G + g)) * 256 + lane * 4);
        p.x += q.x; p.y += q.y; p.z += q.z; p.w += q.w;
    }
    int d0 = lane * 4;
    float acc = p.x * lw[d0 * L + l] + p.y * lw[(d0 + 1) * L + l] +
                p.z * lw[(d0 + 2) * L + l] + p.w * lw[(d0 + 3) * L + l];
#pragma unroll
    for (int off = 32; off >= 1; off >>= 1) acc += __shfl_xor(acc, off);
    if (lane == 0) out[i] = acc / fmaxf(cnt[g], 1.0f) + lb[l];
}

extern "C" void kernel_launch(void* const* d_in, const int* in_sizes, int n_in,
                              void* d_out, int out_size, void* d_ws, size_t ws_size,
                              hipStream_t stream) {
    const float* x   = (const float*)d_in[0];
    const int*   ei  = (const int*)d_in[1];
    const int*   bat = (const int*)d_in[2];
    const float* W1  = (const float*)d_in[3];
    const float* as1 = (const float*)d_in[4];
    const float* ad1 = (const float*)d_in[5];
    const float* b1  = (const float*)d_in[6];
    const float* W2  = (const float*)d_in[7];
    const float* as2 = (const float*)d_in[8];
    const float* ad2 = (const float*)d_in[9];
    const float* b2  = (const float*)d_in[10];
    const float* lw  = (const float*)d_in[11];
    const float* lb  = (const float*)d_in[12];
    float* out = (float*)d_out;

    const int N = in_sizes[2];        // 10000
    const int E = in_sizes[1] / 2;    // 320000
    const int G = 64, L = 10;
    const int Etot = E + N;

    // workspace layout (floats)
    float* A    = (float*)d_ws;              // [N,256] h1 then h2
    float* B    = A + (size_t)N * 256;       // [N,256] out1 then out2
    float* als1 = B + (size_t)N * 256;       // [N,16]
    float* ald1 = als1 + (size_t)N * 16;
    float* als2 = ald1 + (size_t)N * 16;     // [N]
    float* ald2 = als2 + N;
    float* pooled4 = ald2 + N;               // [4,G,256]
    float* cnt  = pooled4 + (size_t)4 * G * 256;  // [G]
    int* counts = (int*)(cnt + G);           // [N]
    int* rowptr = counts + N;                // [N+1]
    int* cursor = rowptr + N + 1;            // [N]
    int* col    = cursor + N;                // [Etot]

    const int BS = 256;
    auto nb = [](int n, int b) { return (n + b - 1) / b; };
    int nodes4 = nb(N, 4);
    int rows16 = nb(N, 16);

    // ---- CSR build (dst-indexed) ----
    k_zero_i32<<<nb(N, BS), BS, 0, stream>>>(counts, N);
    k_count<<<nb(Etot, BS), BS, 0, stream>>>(ei, E, N, counts);
    k_scan<<<1, 1024, 0, stream>>>(counts, rowptr, N);
    k_copy_i32<<<nb(N, BS), BS, 0, stream>>>(rowptr, cursor, N);
    k_fill_csr<<<nb(Etot, BS), BS, 0, stream>>>(ei, E, N, cursor, col);

    // ---- layer 1 ----
    k_gemm_t<128><<<rows16, BS, 0, stream>>>(x, W1, A, N);
    k_logits1<<<nb(N * 16, BS), BS, 0, stream>>>(A, as1, ad1, als1, ald1, N * 16);
    k_gather_h16<<<nodes4, BS, 0, stream>>>(rowptr, col, A, als1, ald1, b1, B, N);

    // ---- layer 2 ----
    k_gemm_t<256><<<rows16, BS, 0, stream>>>(B, W2, A, N);
    k_logits2<<<nodes4, BS, 0, stream>>>(A, as2, ad2, als2, ald2, N);
    k_gather_h1<<<nodes4, BS, 0, stream>>>(rowptr, col, A, als2, ald2, b2, B, N);

    // ---- pool + final linear ----
    k_pool_seg<<<G * 4, BS, 0, stream>>>(B, bat, pooled4, cnt, N, G);
    k_final<<<nb(G * L, 4), BS, 0, stream>>>(pooled4, cnt, lw, lb, out, G, L);
}